// Round 5
// baseline (76.284 us; speedup 1.0000x reference)
//
#include <hip/hip_runtime.h>
#include <hip/hip_bf16.h>
#include <math.h>

#define BB 4
#define SS 2048
#define EE 1024
#define HH 64
#define BS (BB*SS)   // 8192 rows total

typedef __attribute__((ext_vector_type(8))) short bf16x8;
typedef __attribute__((ext_vector_type(4))) float f32x4;

static __device__ __forceinline__ unsigned int f2b(float f) {
  __hip_bfloat16 h = __float2bfloat16(f);
  unsigned short u;
  __builtin_memcpy(&u, &h, 2);
  return (unsigned int)u;
}

// ---------------------------------------------------------------------------
// Kernel 0: W transpose+convert.  wt[n][e] bf16, n = which*64 + h, e = 0..1023.
// Wq rows pre-scaled by 1/32 (score scale folded into q). Unchanged.
// ---------------------------------------------------------------------------
__global__ __launch_bounds__(256) void wt_prep(const float* __restrict__ Wq,
                                               const float* __restrict__ Wk,
                                               const float* __restrict__ Wv,
                                               unsigned short* __restrict__ wt) {
  __shared__ float tile[64 * 69];
  const int blk = blockIdx.x;
  const int w = blk >> 4;
  const int et = blk & 15;
  const int t = threadIdx.x;
  const float* __restrict__ W = (w == 0) ? Wq : ((w == 1) ? Wk : Wv);

#pragma unroll
  for (int i = 0; i < 4; ++i) {
    const int idx = t + i * 256;
    const int row = idx >> 4;
    const int f4 = idx & 15;
    const float4 v = *(const float4*)(W + ((size_t)(et * 64 + row)) * 64 + f4 * 4);
    tile[row * 69 + f4 * 4 + 0] = v.x;
    tile[row * 69 + f4 * 4 + 1] = v.y;
    tile[row * 69 + f4 * 4 + 2] = v.z;
    tile[row * 69 + f4 * 4 + 3] = v.w;
  }
  __syncthreads();

  const float scale = (w == 0) ? 0.03125f : 1.0f;
  const int h = t >> 2;
  const int eg = (t & 3) * 16;
  unsigned int o[8];
#pragma unroll
  for (int i = 0; i < 8; ++i) {
    const float a = tile[(eg + 2 * i + 0) * 69 + h] * scale;
    const float b = tile[(eg + 2 * i + 1) * 69 + h] * scale;
    o[i] = f2b(a) | (f2b(b) << 16);
  }
  unsigned short* dst = wt + ((size_t)(w * 64 + h)) * 1024 + et * 64 + eg;
  uint4 lo4; lo4.x = o[0]; lo4.y = o[1]; lo4.z = o[2]; lo4.w = o[3];
  uint4 hi4; hi4.x = o[4]; hi4.y = o[5]; hi4.z = o[6]; hi4.w = o[7];
  *(uint4*)dst = lo4;
  *(uint4*)(dst + 8) = hi4;
}

// ---------------------------------------------------------------------------
// Kernel A: QKV projection, bf16 MFMA, NO LDS / NO BARRIERS.
// 256 blocks x 512 threads (8 waves: wm = wv>>2 picks 16 of 32 rows,
// wn = wv&3 picks 48 cols). A-frags: x rows loaded global->reg, cvt to bf16.
// B-frags: wt rows loaded L2->reg (384 KB resident). Depth-4 x prefetch,
// depth-2 W prefetch, all statically indexed (full unroll), zero syncs.
// ---------------------------------------------------------------------------
__global__ __launch_bounds__(512) void qkv_mfma(const float* __restrict__ x,
                                                const unsigned short* __restrict__ wt,
                                                unsigned short* __restrict__ qb,
                                                unsigned short* __restrict__ kbuf,
                                                unsigned short* __restrict__ vtb) {
  const int t = threadIdx.x;
  const int blk = blockIdx.x;
  const int lane = t & 63;
  const int wv = t >> 6;          // 0..7
  const int wm = wv >> 2;         // 0..1 : m-frag
  const int wn = wv & 3;          // 0..3 : n-group (48 cols)
  const int lo = lane & 15, hi = lane >> 4;

  // A: lane (lo,hi) holds x[row = blk*32 + wm*16 + lo][k = kc*32 + hi*8 .. +7]
  const float* __restrict__ xp =
      x + ((size_t)blk * 32 + wm * 16 + lo) * 1024 + hi * 8;
  // B: lane (lo,hi) holds wt[n = wn*48 + nf*16 + lo][k = kc*32 + hi*8 .. +7]
  const unsigned short* __restrict__ wp0 = wt + ((size_t)(wn * 48 + 0 * 16 + lo)) * 1024 + hi * 8;
  const unsigned short* __restrict__ wp1 = wt + ((size_t)(wn * 48 + 1 * 16 + lo)) * 1024 + hi * 8;
  const unsigned short* __restrict__ wp2 = wt + ((size_t)(wn * 48 + 2 * 16 + lo)) * 1024 + hi * 8;

  f32x4 acc[3] = {};
  float4 xa[4], xb[4];            // depth-4 x prefetch (2 float4 per chunk)
  bf16x8 wf[2][3];                // depth-2 W prefetch

#define LX(slot, kc)                                    \
  do {                                                  \
    xa[slot] = *(const float4*)(xp + (kc) * 32);        \
    xb[slot] = *(const float4*)(xp + (kc) * 32 + 4);    \
  } while (0)
#define LW(slot, kc)                                    \
  do {                                                  \
    wf[slot][0] = *(const bf16x8*)(wp0 + (kc) * 32);    \
    wf[slot][1] = *(const bf16x8*)(wp1 + (kc) * 32);    \
    wf[slot][2] = *(const bf16x8*)(wp2 + (kc) * 32);    \
  } while (0)

  LX(0, 0); LX(1, 1); LX(2, 2); LX(3, 3);
  LW(0, 0); LW(1, 1);

#pragma unroll
  for (int kc = 0; kc < 32; ++kc) {
    const int xs = kc & 3;
    const int ws = kc & 1;

    // convert this chunk's x to a bf16 A-frag
    unsigned int aw[4];
    aw[0] = f2b(xa[xs].x) | (f2b(xa[xs].y) << 16);
    aw[1] = f2b(xa[xs].z) | (f2b(xa[xs].w) << 16);
    aw[2] = f2b(xb[xs].x) | (f2b(xb[xs].y) << 16);
    aw[3] = f2b(xb[xs].z) | (f2b(xb[xs].w) << 16);
    bf16x8 af;
    __builtin_memcpy(&af, aw, 16);

    acc[0] = __builtin_amdgcn_mfma_f32_16x16x32_bf16(af, wf[ws][0], acc[0], 0, 0, 0);
    acc[1] = __builtin_amdgcn_mfma_f32_16x16x32_bf16(af, wf[ws][1], acc[1], 0, 0, 0);
    acc[2] = __builtin_amdgcn_mfma_f32_16x16x32_bf16(af, wf[ws][2], acc[2], 0, 0, 0);

    if (kc + 4 < 32) LX(xs, kc + 4);
    if (kc + 2 < 32) LW(ws, kc + 2);
  }
#undef LX
#undef LW

  // epilogue: C[m][n]: m = blk*32 + wm*16 + hi*4 + r, n = wn*48 + nf*16 + lo
  const int m0 = blk * 32 + wm * 16 + hi * 4;
#pragma unroll
  for (int nf = 0; nf < 3; ++nf) {
    const int nb = wn * 48 + nf * 16;
    const int which = nb >> 6;
    const int h = (nb & 63) + lo;
#pragma unroll
    for (int r = 0; r < 4; ++r) {
      const int row = m0 + r;
      const unsigned short v = (unsigned short)f2b(acc[nf][r]);
      if (which == 0) qb[(size_t)row * 64 + h] = v;
      else if (which == 1) kbuf[(size_t)row * 64 + h] = v;
      else vtb[((size_t)(row >> 11) * 64 + h) * 2048 + (row & 2047)] = v;
    }
  }
}

// ---------------------------------------------------------------------------
// Kernel B: causal flash attention, bf16 MFMA, 8-way split-K. Unchanged (R4).
// ---------------------------------------------------------------------------
__global__ __launch_bounds__(512) void attn_mfma(const unsigned short* __restrict__ qb,
                                                 const unsigned short* __restrict__ kbuf,
                                                 const unsigned short* __restrict__ vt,
                                                 float* __restrict__ out) {
  __shared__ __align__(16) float sacc[8][16][64];  // 32 KB
  __shared__ float sml[2][8][16];                  // m, l

  const int t = threadIdx.x;
  const int lane = t & 63;
  const int w = t >> 6;            // 0..7
  const int lo = lane & 15, hi = lane >> 4;
  const int hi4 = hi * 4;

  const int i = blockIdx.x;        // 0..511
  const int batch = i & 3;
  const int tt = i >> 2;           // 0..127
  const int qt = (tt & 1) ? (127 - (tt >> 1)) : (tt >> 1);  // snake

  const unsigned short* Qb = qb   + (size_t)batch * SS * 64;
  const unsigned short* Kb = kbuf + (size_t)batch * SS * 64;
  const unsigned short* Vt = vt   + (size_t)batch * 64 * SS;

  const int q = qt * 16 + lo;

  const bf16x8 qf0 = *(const bf16x8*)(Qb + (size_t)q * 64 + hi * 8);
  const bf16x8 qf1 = *(const bf16x8*)(Qb + (size_t)q * 64 + 32 + hi * 8);

  f32x4 acc[4] = {};
  float m = -1e30f, l = 0.f;

  const int kend = qt * 16 + 16;
  for (int kbase = w * 64; kbase < kend; kbase += 512) {
    f32x4 s[4];
#pragma unroll
    for (int j0 = 0; j0 < 4; ++j0) {
      const unsigned short* Krow = Kb + (size_t)(kbase + j0 * 16 + lo) * 64 + hi * 8;
      const bf16x8 ka = *(const bf16x8*)(Krow);
      const bf16x8 kb2 = *(const bf16x8*)(Krow + 32);
      f32x4 c = {};
      c = __builtin_amdgcn_mfma_f32_16x16x32_bf16(ka, qf0, c, 0, 0, 0);
      c = __builtin_amdgcn_mfma_f32_16x16x32_bf16(kb2, qf1, c, 0, 0, 0);
      s[j0] = c;
    }

    if (kbase + 64 >= kend) {
#pragma unroll
      for (int j0 = 0; j0 < 4; ++j0)
#pragma unroll
        for (int r = 0; r < 4; ++r) {
          const int key = kbase + j0 * 16 + hi4 + r;
          s[j0][r] = (key > q) ? -1e30f : s[j0][r];
        }
    }

    float mx = fmaxf(fmaxf(s[0][0], s[0][1]), fmaxf(s[0][2], s[0][3]));
    mx = fmaxf(mx, fmaxf(fmaxf(s[1][0], s[1][1]), fmaxf(s[1][2], s[1][3])));
    mx = fmaxf(mx, fmaxf(fmaxf(s[2][0], s[2][1]), fmaxf(s[2][2], s[2][3])));
    mx = fmaxf(mx, fmaxf(fmaxf(s[3][0], s[3][1]), fmaxf(s[3][2], s[3][3])));
    mx = fmaxf(mx, __shfl_xor(mx, 16));
    mx = fmaxf(mx, __shfl_xor(mx, 32));

    const float mnew = fmaxf(m, mx);
    const float scale = __expf(m - mnew);
    m = mnew;

    unsigned int W[4][2];
    float ps = 0.f;
#pragma unroll
    for (int j0 = 0; j0 < 4; ++j0) {
      const float p0 = __expf(s[j0][0] - mnew);
      const float p1 = __expf(s[j0][1] - mnew);
      const float p2 = __expf(s[j0][2] - mnew);
      const float p3 = __expf(s[j0][3] - mnew);
      ps += (p0 + p1) + (p2 + p3);
      W[j0][0] = f2b(p0) | (f2b(p1) << 16);
      W[j0][1] = f2b(p2) | (f2b(p3) << 16);
    }
    ps += __shfl_xor(ps, 16);
    ps += __shfl_xor(ps, 32);
    l = l * scale + ps;

#pragma unroll
    for (int j = 0; j < 4; ++j) {
      acc[j][0] *= scale; acc[j][1] *= scale;
      acc[j][2] *= scale; acc[j][3] *= scale;
    }

#pragma unroll
    for (int kc = 0; kc < 2; ++kc) {
      unsigned int wreg[4];
#pragma unroll
      for (int wi = 0; wi < 4; ++wi) {
        const int src = lo + ((lane & 16) << 1) + ((wi >> 1) << 4);
        const unsigned int t0 = (unsigned int)__shfl((int)W[2 * kc + 0][wi & 1], src);
        const unsigned int t1 = (unsigned int)__shfl((int)W[2 * kc + 1][wi & 1], src);
        wreg[wi] = (hi < 2) ? t0 : t1;
      }
      bf16x8 pB;
      __builtin_memcpy(&pB, wreg, 16);
#pragma unroll
      for (int j = 0; j < 4; ++j) {
        const bf16x8 va = *(const bf16x8*)(Vt + (size_t)(j * 16 + lo) * SS +
                                           kbase + kc * 32 + hi * 8);
        acc[j] = __builtin_amdgcn_mfma_f32_16x16x32_bf16(va, pB, acc[j], 0, 0, 0);
      }
    }
  }

  if (hi == 0) { sml[0][w][lo] = m; sml[1][w][lo] = l; }
#pragma unroll
  for (int j = 0; j < 4; ++j)
    *(f32x4*)&sacc[w][lo][j * 16 + hi4] = acc[j];
  __syncthreads();

  const int row = t >> 5;
  const int d0 = (t & 31) * 2;
  float mstar = sml[0][0][row];
#pragma unroll
  for (int ww = 1; ww < 8; ++ww) mstar = fmaxf(mstar, sml[0][ww][row]);
  float lstar = 0.f, o0 = 0.f, o1 = 0.f;
#pragma unroll
  for (int ww = 0; ww < 8; ++ww) {
    const float f = __expf(sml[0][ww][row] - mstar);
    lstar += sml[1][ww][row] * f;
    const float2 a2 = *(const float2*)&sacc[ww][row][d0];
    o0 += a2.x * f;
    o1 += a2.y * f;
  }
  const float rl = 1.0f / lstar;
  float2 o; o.x = o0 * rl; o.y = o1 * rl;
  *(float2*)(out + ((size_t)batch * SS + qt * 16 + row) * 64 + d0) = o;
}

extern "C" void kernel_launch(void* const* d_in, const int* in_sizes, int n_in,
                              void* d_out, int out_size, void* d_ws, size_t ws_size,
                              hipStream_t stream) {
  const float* x  = (const float*)d_in[0];
  const float* Wq = (const float*)d_in[1];
  const float* Wk = (const float*)d_in[2];
  const float* Wv = (const float*)d_in[3];
  float* outp = (float*)d_out;

  unsigned short* qb = (unsigned short*)d_ws;           // 1 MB
  unsigned short* kb = qb + (size_t)BS * 64;            // 1 MB
  unsigned short* vt = kb + (size_t)BS * 64;            // 1 MB
  unsigned short* wt = vt + (size_t)BS * 64;            // 384 KB

  wt_prep<<<48, 256, 0, stream>>>(Wq, Wk, Wv, wt);
  qkv_mfma<<<BS / 32, 512, 0, stream>>>(x, wt, qb, kb, vt);
  attn_mfma<<<512, 512, 0, stream>>>(qb, kb, vt, outp);
}

// Round 6
// 64.287 us; speedup vs baseline: 1.1866x; 1.1866x over previous
//
#include <hip/hip_runtime.h>
#include <hip/hip_bf16.h>
#include <math.h>

#define BB 4
#define SS 2048
#define EE 1024
#define HH 64
#define BS (BB*SS)   // 8192 rows total

typedef __attribute__((ext_vector_type(8))) short bf16x8;
typedef __attribute__((ext_vector_type(4))) float f32x4;

static __device__ __forceinline__ unsigned int f2b(float f) {
  __hip_bfloat16 h = __float2bfloat16(f);
  unsigned short u;
  __builtin_memcpy(&u, &h, 2);
  return (unsigned int)u;
}

// ---------------------------------------------------------------------------
// Kernel 0: W transpose+convert.  wt[n][e] bf16, n = which*64 + h, e = 0..1023.
// Wq rows pre-scaled by (1/32)*log2(e): scores come out in the exp2 domain.
// ---------------------------------------------------------------------------
__global__ __launch_bounds__(256) void wt_prep(const float* __restrict__ Wq,
                                               const float* __restrict__ Wk,
                                               const float* __restrict__ Wv,
                                               unsigned short* __restrict__ wt) {
  __shared__ float tile[64 * 69];
  const int blk = blockIdx.x;
  const int w = blk >> 4;
  const int et = blk & 15;
  const int t = threadIdx.x;
  const float* __restrict__ W = (w == 0) ? Wq : ((w == 1) ? Wk : Wv);

#pragma unroll
  for (int i = 0; i < 4; ++i) {
    const int idx = t + i * 256;
    const int row = idx >> 4;
    const int f4 = idx & 15;
    const float4 v = *(const float4*)(W + ((size_t)(et * 64 + row)) * 64 + f4 * 4);
    tile[row * 69 + f4 * 4 + 0] = v.x;
    tile[row * 69 + f4 * 4 + 1] = v.y;
    tile[row * 69 + f4 * 4 + 2] = v.z;
    tile[row * 69 + f4 * 4 + 3] = v.w;
  }
  __syncthreads();

  const float scale = (w == 0) ? 0.03125f * 1.4426950408889634f : 1.0f;
  const int h = t >> 2;
  const int eg = (t & 3) * 16;
  unsigned int o[8];
#pragma unroll
  for (int i = 0; i < 8; ++i) {
    const float a = tile[(eg + 2 * i + 0) * 69 + h] * scale;
    const float b = tile[(eg + 2 * i + 1) * 69 + h] * scale;
    o[i] = f2b(a) | (f2b(b) << 16);
  }
  unsigned short* dst = wt + ((size_t)(w * 64 + h)) * 1024 + et * 64 + eg;
  uint4 lo4; lo4.x = o[0]; lo4.y = o[1]; lo4.z = o[2]; lo4.w = o[3];
  uint4 hi4; hi4.x = o[4]; hi4.y = o[5]; hi4.z = o[6]; hi4.w = o[7];
  *(uint4*)dst = lo4;
  *(uint4*)(dst + 8) = hi4;
}

// ---------------------------------------------------------------------------
// Kernel A: QKV projection, bf16 MFMA.  [8192x1024] x [1024x192].
// 512 blocks x 256 threads (4 waves; wave wn owns 48 cols). BM=16, BK=128.
// A: x staged fp32->bf16 through 2x4KB XOR-swizzled LDS (double-buffered,
//    ONE barrier per K-step, 8 steps total).
// B: wt frags global(L2)->named reg arrays, double-buffered one step ahead
//    (counted vmcnt; barrier does NOT drain them).
// ---------------------------------------------------------------------------
__global__ __launch_bounds__(256) void qkv_mfma(const float* __restrict__ x,
                                                const unsigned short* __restrict__ wt,
                                                unsigned short* __restrict__ qb,
                                                unsigned short* __restrict__ kbuf,
                                                unsigned short* __restrict__ vtb) {
  __shared__ char xs[2][4096];   // [16 rows][128 k] bf16, swizzled
  const int t = threadIdx.x;
  const int blk = blockIdx.x;
  const int lane = t & 63;
  const int wn = t >> 6;          // 0..3 : n-group (48 cols)
  const int lo = lane & 15, hi = lane >> 4;

  // x staging: thread t -> row t>>4, two float4 at cols (t&15)*4 and +64
  const int xrow = t >> 4;
  const int xc = (t & 15) * 4;
  const float* __restrict__ xsrc = x + ((size_t)blk * 16 + xrow) * 1024 + xc;
  const int xswz = (xrow & 7) << 4;
  const int wo0 = xrow * 256 + ((xc * 2) ^ xswz);
  const int wo1 = xrow * 256 + ((xc * 2 + 128) ^ xswz);

  // W frag pointers: row wn*48 + nf*16 + lo, k-slice hi*8
  const unsigned short* __restrict__ wp0 = wt + ((size_t)(wn * 48 +  0 + lo)) * 1024 + hi * 8;
  const unsigned short* __restrict__ wp1 = wt + ((size_t)(wn * 48 + 16 + lo)) * 1024 + hi * 8;
  const unsigned short* __restrict__ wp2 = wt + ((size_t)(wn * 48 + 32 + lo)) * 1024 + hi * 8;

  f32x4 acc[3] = {};
  bf16x8 wfA[12], wfB[12];        // B-frag double buffer (step-parity)
  float4 xr0, xr1;

#define LW(arr, s)                                                   \
  _Pragma("unroll")                                                  \
  for (int c = 0; c < 4; ++c) {                                      \
    arr[c * 3 + 0] = *(const bf16x8*)(wp0 + ((s) * 4 + c) * 32);     \
    arr[c * 3 + 1] = *(const bf16x8*)(wp1 + ((s) * 4 + c) * 32);     \
    arr[c * 3 + 2] = *(const bf16x8*)(wp2 + ((s) * 4 + c) * 32);     \
  }
#define LX(s)                                                        \
  do {                                                               \
    xr0 = *(const float4*)(xsrc + (s) * 128);                        \
    xr1 = *(const float4*)(xsrc + (s) * 128 + 64);                   \
  } while (0)
#define WX(buf)                                                      \
  do {                                                               \
    uint2 a, b;                                                      \
    a.x = f2b(xr0.x) | (f2b(xr0.y) << 16);                           \
    a.y = f2b(xr0.z) | (f2b(xr0.w) << 16);                           \
    b.x = f2b(xr1.x) | (f2b(xr1.y) << 16);                           \
    b.y = f2b(xr1.z) | (f2b(xr1.w) << 16);                           \
    *(uint2*)&xs[buf][wo0] = a;                                      \
    *(uint2*)&xs[buf][wo1] = b;                                      \
  } while (0)
#define COMP(buf, arr)                                               \
  _Pragma("unroll")                                                  \
  for (int c = 0; c < 4; ++c) {                                      \
    const bf16x8 af = *(const bf16x8*)&xs[buf][lo * 256 +            \
        ((c * 64 + hi * 16) ^ ((lo & 7) << 4))];                     \
    acc[0] = __builtin_amdgcn_mfma_f32_16x16x32_bf16(af, arr[c*3+0], acc[0], 0, 0, 0); \
    acc[1] = __builtin_amdgcn_mfma_f32_16x16x32_bf16(af, arr[c*3+1], acc[1], 0, 0, 0); \
    acc[2] = __builtin_amdgcn_mfma_f32_16x16x32_bf16(af, arr[c*3+2], acc[2], 0, 0, 0); \
  }

  // prologue: stage step 0
  LX(0);
  WX(0);
  LW(wfA, 0);
  __syncthreads();

#pragma unroll
  for (int s = 0; s < 8; ++s) {
    if (s < 7) LX(s + 1);
    if (s & 1) {
      if (s < 7) LW(wfA, s + 1);
      COMP(1, wfB);
    } else {
      if (s < 7) LW(wfB, s + 1);
      COMP(0, wfA);
    }
    if (s < 7) WX((s + 1) & 1);
    __syncthreads();
  }
#undef LW
#undef LX
#undef WX
#undef COMP

  // epilogue: C[m][n]: m = blk*16 + hi*4 + r, n = wn*48 + nf*16 + lo
  const int m0 = blk * 16 + hi * 4;
#pragma unroll
  for (int nf = 0; nf < 3; ++nf) {
    const int nb = wn * 48 + nf * 16;
    const int which = nb >> 6;
    const int h = (nb & 63) + lo;
#pragma unroll
    for (int r = 0; r < 4; ++r) {
      const int row = m0 + r;
      const unsigned short v = (unsigned short)f2b(acc[nf][r]);
      if (which == 0) qb[(size_t)row * 64 + h] = v;
      else if (which == 1) kbuf[(size_t)row * 64 + h] = v;
      else vtb[((size_t)(row >> 11) * 64 + h) * 2048 + (row & 2047)] = v;
    }
  }
}

// ---------------------------------------------------------------------------
// Kernel B: causal flash attention, bf16 MFMA, 8-way split-K.
// R4 structure + exp2-domain softmax (q pre-scaled by log2e) + exact
// skip-rescale (only rescale acc/l when the running max actually grows).
// ---------------------------------------------------------------------------
__global__ __launch_bounds__(512) void attn_mfma(const unsigned short* __restrict__ qb,
                                                 const unsigned short* __restrict__ kbuf,
                                                 const unsigned short* __restrict__ vt,
                                                 float* __restrict__ out) {
  __shared__ __align__(16) float sacc[8][16][64];  // 32 KB
  __shared__ float sml[2][8][16];                  // m, l

  const int t = threadIdx.x;
  const int lane = t & 63;
  const int w = t >> 6;            // 0..7
  const int lo = lane & 15, hi = lane >> 4;
  const int hi4 = hi * 4;

  const int i = blockIdx.x;        // 0..511
  const int batch = i & 3;
  const int tt = i >> 2;           // 0..127
  const int qt = (tt & 1) ? (127 - (tt >> 1)) : (tt >> 1);  // snake

  const unsigned short* Qb = qb   + (size_t)batch * SS * 64;
  const unsigned short* Kb = kbuf + (size_t)batch * SS * 64;
  const unsigned short* Vt = vt   + (size_t)batch * 64 * SS;

  const int q = qt * 16 + lo;

  const bf16x8 qf0 = *(const bf16x8*)(Qb + (size_t)q * 64 + hi * 8);
  const bf16x8 qf1 = *(const bf16x8*)(Qb + (size_t)q * 64 + 32 + hi * 8);

  f32x4 acc[4] = {};
  float m = -1e30f, l = 0.f;

  const int kend = qt * 16 + 16;
  for (int kbase = w * 64; kbase < kend; kbase += 512) {
    // ---- S^T = K · Q^T (scores already in log2 domain) ----
    f32x4 s[4];
#pragma unroll
    for (int j0 = 0; j0 < 4; ++j0) {
      const unsigned short* Krow = Kb + (size_t)(kbase + j0 * 16 + lo) * 64 + hi * 8;
      const bf16x8 ka = *(const bf16x8*)(Krow);
      const bf16x8 kb2 = *(const bf16x8*)(Krow + 32);
      f32x4 c = {};
      c = __builtin_amdgcn_mfma_f32_16x16x32_bf16(ka, qf0, c, 0, 0, 0);
      c = __builtin_amdgcn_mfma_f32_16x16x32_bf16(kb2, qf1, c, 0, 0, 0);
      s[j0] = c;
    }

    if (kbase + 64 >= kend) {      // only the diagonal-touching chunk masks
#pragma unroll
      for (int j0 = 0; j0 < 4; ++j0)
#pragma unroll
        for (int r = 0; r < 4; ++r) {
          const int key = kbase + j0 * 16 + hi4 + r;
          s[j0][r] = (key > q) ? -1e30f : s[j0][r];
        }
    }

    // ---- row max over 64 keys ----
    float mx = fmaxf(fmaxf(s[0][0], s[0][1]), fmaxf(s[0][2], s[0][3]));
    mx = fmaxf(mx, fmaxf(fmaxf(s[1][0], s[1][1]), fmaxf(s[1][2], s[1][3])));
    mx = fmaxf(mx, fmaxf(fmaxf(s[2][0], s[2][1]), fmaxf(s[2][2], s[2][3])));
    mx = fmaxf(mx, fmaxf(fmaxf(s[3][0], s[3][1]), fmaxf(s[3][2], s[3][3])));
    mx = fmaxf(mx, __shfl_xor(mx, 16));
    mx = fmaxf(mx, __shfl_xor(mx, 32));

    // ---- exact skip-rescale: only touch acc/l when max grows ----
    if (__any(mx > m)) {
      const float mnew = fmaxf(m, mx);
      const float sc = exp2f(m - mnew);   // 0 on first chunk
      m = mnew;
      l *= sc;
#pragma unroll
      for (int j = 0; j < 4; ++j) {
        acc[j][0] *= sc; acc[j][1] *= sc;
        acc[j][2] *= sc; acc[j][3] *= sc;
      }
    }

    // ---- p = exp2(s - m), pack to bf16 pairs, row-sum ----
    unsigned int W[4][2];
    float ps = 0.f;
#pragma unroll
    for (int j0 = 0; j0 < 4; ++j0) {
      const float p0 = exp2f(s[j0][0] - m);
      const float p1 = exp2f(s[j0][1] - m);
      const float p2 = exp2f(s[j0][2] - m);
      const float p3 = exp2f(s[j0][3] - m);
      ps += (p0 + p1) + (p2 + p3);
      W[j0][0] = f2b(p0) | (f2b(p1) << 16);
      W[j0][1] = f2b(p2) | (f2b(p3) << 16);
    }
    ps += __shfl_xor(ps, 16);
    ps += __shfl_xor(ps, 32);
    l += ps;

    // ---- P^T B-frags via register exchange + PV MFMAs ----
#pragma unroll
    for (int kc = 0; kc < 2; ++kc) {
      unsigned int wreg[4];
#pragma unroll
      for (int wi = 0; wi < 4; ++wi) {
        const int src = lo + ((lane & 16) << 1) + ((wi >> 1) << 4);
        const unsigned int t0 = (unsigned int)__shfl((int)W[2 * kc + 0][wi & 1], src);
        const unsigned int t1 = (unsigned int)__shfl((int)W[2 * kc + 1][wi & 1], src);
        wreg[wi] = (hi < 2) ? t0 : t1;
      }
      bf16x8 pB;
      __builtin_memcpy(&pB, wreg, 16);
#pragma unroll
      for (int j = 0; j < 4; ++j) {
        const bf16x8 va = *(const bf16x8*)(Vt + (size_t)(j * 16 + lo) * SS +
                                           kbase + kc * 32 + hi * 8);
        acc[j] = __builtin_amdgcn_mfma_f32_16x16x32_bf16(va, pB, acc[j], 0, 0, 0);
      }
    }
  }

  // ---- publish per-wave partials ----
  if (hi == 0) { sml[0][w][lo] = m; sml[1][w][lo] = l; }
#pragma unroll
  for (int j = 0; j < 4; ++j)
    *(f32x4*)&sacc[w][lo][j * 16 + hi4] = acc[j];
  __syncthreads();

  // ---- merge 8 partials (exp2 domain) ----
  const int row = t >> 5;
  const int d0 = (t & 31) * 2;
  float mstar = sml[0][0][row];
#pragma unroll
  for (int ww = 1; ww < 8; ++ww) mstar = fmaxf(mstar, sml[0][ww][row]);
  float lstar = 0.f, o0 = 0.f, o1 = 0.f;
#pragma unroll
  for (int ww = 0; ww < 8; ++ww) {
    const float f = exp2f(sml[0][ww][row] - mstar);
    lstar += sml[1][ww][row] * f;
    const float2 a2 = *(const float2*)&sacc[ww][row][d0];
    o0 += a2.x * f;
    o1 += a2.y * f;
  }
  const float rl = 1.0f / lstar;
  float2 o; o.x = o0 * rl; o.y = o1 * rl;
  *(float2*)(out + ((size_t)batch * SS + qt * 16 + row) * 64 + d0) = o;
}

extern "C" void kernel_launch(void* const* d_in, const int* in_sizes, int n_in,
                              void* d_out, int out_size, void* d_ws, size_t ws_size,
                              hipStream_t stream) {
  const float* x  = (const float*)d_in[0];
  const float* Wq = (const float*)d_in[1];
  const float* Wk = (const float*)d_in[2];
  const float* Wv = (const float*)d_in[3];
  float* outp = (float*)d_out;

  unsigned short* qb = (unsigned short*)d_ws;           // 1 MB
  unsigned short* kb = qb + (size_t)BS * 64;            // 1 MB
  unsigned short* vt = kb + (size_t)BS * 64;            // 1 MB
  unsigned short* wt = vt + (size_t)BS * 64;            // 384 KB

  wt_prep<<<48, 256, 0, stream>>>(Wq, Wk, Wv, wt);
  qkv_mfma<<<BS / 16, 256, 0, stream>>>(x, wt, qb, kb, vt);
  attn_mfma<<<512, 512, 0, stream>>>(qb, kb, vt, outp);
}